// Round 1
// baseline (1753.132 us; speedup 1.0000x reference)
//
#include <hip/hip_runtime.h>
#include <cstddef>

// Shapes (fixed by the problem): B=4, H=W=64, C=Cc=Cf=F=256, G=8, K=9.
constexpr int NB   = 4;
constexpr int HH   = 64;
constexpr int WW   = 64;
constexpr int CCH  = 256;      // channels
constexpr int HWP  = HH * WW;  // 4096 pixels per image
constexpr int OMC  = 216;      // G*3*K = 8*27

// ---------------------------------------------------------------------------
// Stage 1: pooled mean over H,W  ->  attn = sigmoid(pooled @ w_att) ; scale=attn+1
// one block per batch, 1024 threads (4 row-chunks x 256 channels)
// ---------------------------------------------------------------------------
__global__ __launch_bounds__(1024) void pool_attn_kernel(
    const float* __restrict__ fine, const float* __restrict__ w_att,
    float* __restrict__ scale) {
  __shared__ float red[1024];
  __shared__ float pl[256];
  int b = blockIdx.x;
  int t = threadIdx.x;
  int c = t & 255;
  int chunk = t >> 8;
  const float* src = fine + (size_t)b * HWP * CCH;
  float s = 0.f;
  for (int p = chunk * 1024; p < chunk * 1024 + 1024; ++p)
    s += src[(size_t)p * CCH + c];
  red[t] = s;
  __syncthreads();
  if (t < 256)
    pl[t] = (red[t] + red[t + 256] + red[t + 512] + red[t + 768]) * (1.0f / 4096.0f);
  __syncthreads();
  if (t < 256) {
    float acc = 0.f;
    for (int ci = 0; ci < 256; ++ci)
      acc += pl[ci] * w_att[ci * 256 + t];
    scale[b * 256 + t] = 1.0f + 1.0f / (1.0f + expf(-acc));
  }
}

// ---------------------------------------------------------------------------
// Stage 2: bilinear upsample 32x32 -> 64x64 (jax.image.resize半-pixel centers,
// edge taps renormalize == coordinate clamp). One block per output pixel.
// ---------------------------------------------------------------------------
__global__ __launch_bounds__(256) void upsample_kernel(
    const float* __restrict__ coarse, float* __restrict__ up) {
  int m = blockIdx.x;  // 0..16383 : b*4096 + h*64 + w
  int c = threadIdx.x;
  int b = m >> 12, h = (m >> 6) & 63, w = m & 63;
  float cy = fminf(fmaxf(h * 0.5f - 0.25f, 0.f), 31.f);
  float cx = fminf(fmaxf(w * 0.5f - 0.25f, 0.f), 31.f);
  int y0 = (int)cy, x0 = (int)cx;  // cy,cx >= 0 so trunc == floor
  float fy = cy - y0, fx = cx - x0;
  int y1 = min(y0 + 1, 31), x1 = min(x0 + 1, 31);
  const float* base = coarse + (size_t)b * 32 * 32 * CCH;
  float v00 = base[(y0 * 32 + x0) * CCH + c];
  float v01 = base[(y0 * 32 + x1) * CCH + c];
  float v10 = base[(y1 * 32 + x0) * CCH + c];
  float v11 = base[(y1 * 32 + x1) * CCH + c];
  float top = v00 + (v01 - v00) * fx;
  float bot = v10 + (v11 - v10) * fx;
  up[(size_t)m * CCH + c] = top + (bot - top) * fy;
}

// ---------------------------------------------------------------------------
// Stage 3: fine_cal = (fine * scale[b,c]) @ w_sel   M=16384 K=256 N=256
// 64x64 tile, BK=16, 256 threads, 4x4 micro-tile.
// ---------------------------------------------------------------------------
__global__ __launch_bounds__(256) void gemm_finecal(
    const float* __restrict__ fine, const float* __restrict__ scale,
    const float* __restrict__ w_sel, float* __restrict__ outp) {
  __shared__ float As[16][68];
  __shared__ float Bs[16][64];
  int n0 = blockIdx.x * 64;
  int m0 = blockIdx.y * 64;
  int t = threadIdx.x, tx = t & 15, ty = t >> 4;
  int bb = m0 >> 12;  // batch; 64 | 4096 so tiles never straddle
  float acc[4][4] = {};
  for (int k0 = 0; k0 < 256; k0 += 16) {
    for (int i = t; i < 64 * 16; i += 256) {
      int kk = i & 15, row = i >> 4;
      As[kk][row] = fine[(size_t)(m0 + row) * 256 + k0 + kk] * scale[bb * 256 + k0 + kk];
    }
    for (int i = t; i < 16 * 64; i += 256) {
      int col = i & 63, kk = i >> 6;
      Bs[kk][col] = w_sel[(size_t)(k0 + kk) * 256 + n0 + col];
    }
    __syncthreads();
#pragma unroll
    for (int kk = 0; kk < 16; ++kk) {
      float4 a4 = *(const float4*)&As[kk][ty * 4];
      float4 b4 = *(const float4*)&Bs[kk][tx * 4];
      float av[4] = {a4.x, a4.y, a4.z, a4.w};
      float bv[4] = {b4.x, b4.y, b4.z, b4.w};
#pragma unroll
      for (int i = 0; i < 4; ++i)
#pragma unroll
        for (int j = 0; j < 4; ++j) acc[i][j] += av[i] * bv[j];
    }
    __syncthreads();
  }
#pragma unroll
  for (int i = 0; i < 4; ++i) {
    float4 v = make_float4(acc[i][0], acc[i][1], acc[i][2], acc[i][3]);
    *(float4*)&outp[(size_t)(m0 + ty * 4 + i) * 256 + n0 + tx * 4] = v;
  }
}

// ---------------------------------------------------------------------------
// Stage 4: align = concat(fine_cal, 2*coarse_up) @ w_off   M=16384 K=512 N=512
// ---------------------------------------------------------------------------
__global__ __launch_bounds__(256) void gemm_align(
    const float* __restrict__ finecal, const float* __restrict__ up,
    const float* __restrict__ w_off, float* __restrict__ outp) {
  __shared__ float As[16][68];
  __shared__ float Bs[16][64];
  int n0 = blockIdx.x * 64;
  int m0 = blockIdx.y * 64;
  int t = threadIdx.x, tx = t & 15, ty = t >> 4;
  float acc[4][4] = {};
  for (int k0 = 0; k0 < 512; k0 += 16) {
    const float* Asrc = (k0 < 256) ? finecal : up;
    float amul = (k0 < 256) ? 1.f : 2.f;
    int kbase = (k0 < 256) ? k0 : (k0 - 256);
    for (int i = t; i < 64 * 16; i += 256) {
      int kk = i & 15, row = i >> 4;
      As[kk][row] = Asrc[(size_t)(m0 + row) * 256 + kbase + kk] * amul;
    }
    for (int i = t; i < 16 * 64; i += 256) {
      int col = i & 63, kk = i >> 6;
      Bs[kk][col] = w_off[(size_t)(k0 + kk) * 512 + n0 + col];
    }
    __syncthreads();
#pragma unroll
    for (int kk = 0; kk < 16; ++kk) {
      float4 a4 = *(const float4*)&As[kk][ty * 4];
      float4 b4 = *(const float4*)&Bs[kk][tx * 4];
      float av[4] = {a4.x, a4.y, a4.z, a4.w};
      float bv[4] = {b4.x, b4.y, b4.z, b4.w};
#pragma unroll
      for (int i = 0; i < 4; ++i)
#pragma unroll
        for (int j = 0; j < 4; ++j) acc[i][j] += av[i] * bv[j];
    }
    __syncthreads();
  }
#pragma unroll
  for (int i = 0; i < 4; ++i) {
    float4 v = make_float4(acc[i][0], acc[i][1], acc[i][2], acc[i][3]);
    *(float4*)&outp[(size_t)(m0 + ty * 4 + i) * 512 + n0 + tx * 4] = v;
  }
}

// ---------------------------------------------------------------------------
// Stage 5: om = conv3x3_same(align, w_om) + b_om   [16384, 216], Cin=512
// Block = 16 consecutive pixels in one image row; thread t = output channel.
// Each thread register-blocks all 16 pixels; A staged per (dy, 64-ch chunk).
// ---------------------------------------------------------------------------
__global__ __launch_bounds__(256) void om_conv_kernel(
    const float* __restrict__ align, const float* __restrict__ w_om,
    const float* __restrict__ b_om, float* __restrict__ om) {
  __shared__ float Arow[64][20];  // [cc][pos], pos = w0-1 .. w0+16 (18 used)
  int blk = blockIdx.x;           // 1024 blocks
  int bh = blk >> 2;              // b*64 + h
  int w0 = (blk & 3) * 16;
  int h = bh & 63;
  int t = threadIdx.x;            // output channel (active < 216)
  float bias = (t < OMC) ? b_om[t] : 0.f;
  float acc[16];
#pragma unroll
  for (int p = 0; p < 16; ++p) acc[p] = bias;
  for (int dy = -1; dy <= 1; ++dy) {
    int y = h + dy;
    if (y < 0 || y > 63) continue;  // uniform across block
    const float* src = align + (size_t)(bh + dy) * 64 * 512;  // row (b, y)
    for (int c0 = 0; c0 < 512; c0 += 64) {
      __syncthreads();
      for (int i = t; i < 18 * 64; i += 256) {
        int cc = i & 63, pos = i >> 6;
        int wpos = w0 - 1 + pos;
        float v = 0.f;
        if (wpos >= 0 && wpos <= 63) v = src[(size_t)wpos * 512 + c0 + cc];
        Arow[cc][pos] = v;
      }
      __syncthreads();
      if (t < OMC) {
        for (int cc = 0; cc < 64; ++cc) {
          float a[18];
          float4 q0 = *(const float4*)&Arow[cc][0];
          float4 q1 = *(const float4*)&Arow[cc][4];
          float4 q2 = *(const float4*)&Arow[cc][8];
          float4 q3 = *(const float4*)&Arow[cc][12];
          a[0] = q0.x; a[1] = q0.y; a[2] = q0.z; a[3] = q0.w;
          a[4] = q1.x; a[5] = q1.y; a[6] = q1.z; a[7] = q1.w;
          a[8] = q2.x; a[9] = q2.y; a[10] = q2.z; a[11] = q2.w;
          a[12] = q3.x; a[13] = q3.y; a[14] = q3.z; a[15] = q3.w;
          a[16] = Arow[cc][16]; a[17] = Arow[cc][17];
#pragma unroll
          for (int dx = 0; dx < 3; ++dx) {
            float wv = w_om[(size_t)(((dy + 1) * 3 + dx) * 512 + c0 + cc) * OMC + t];
#pragma unroll
            for (int p = 0; p < 16; ++p) acc[p] += a[p + dx] * wv;
          }
        }
      }
    }
  }
  if (t < OMC) {
    int m = bh * 64 + w0;
    for (int p = 0; p < 16; ++p)
      om[(size_t)(m + p) * OMC + t] = acc[p];
  }
}

// ---------------------------------------------------------------------------
// Stage 6: deformable sample (bilinear, zero-pad, mask) + einsum + bias + relu
//          + residual fine_cal.  Block = 8 consecutive pixels, 256 threads.
// ---------------------------------------------------------------------------
__global__ __launch_bounds__(256) void dcn_kernel(
    const float* __restrict__ om, const float* __restrict__ up,
    const float* __restrict__ w_dcn, const float* __restrict__ b_dcn,
    const float* __restrict__ finecal, float* __restrict__ outp) {
  __shared__ float syA[576], sxA[576], mkA[576];  // [p][g][k] : 8*8*9
  __shared__ float smp[256 * 12];                 // [c][p], stride 12 (pad)
  int blk = blockIdx.x;  // 2048 blocks
  int m0 = blk * 8;
  int b = m0 >> 12;
  int h = (m0 >> 6) & 63;
  int w0 = m0 & 63;
  int t = threadIdx.x;
  // Precompute sample coords + masks for all (pixel, group, tap)
  for (int i = t; i < 576; i += 256) {
    int p = i / 72;
    int r = i - p * 72;
    int g = r / 9;
    int k = r - g * 9;
    const float* omr = om + (size_t)(m0 + p) * OMC;
    float dy = omr[g * 18 + k * 2];
    float dx = omr[g * 18 + k * 2 + 1];
    float mk = 1.0f / (1.0f + expf(-omr[144 + g * 9 + k]));
    int ky = k / 3;
    int kx = k - ky * 3;
    syA[i] = (float)(h + ky - 1) + dy;
    sxA[i] = (float)(w0 + p + kx - 1) + dx;
    mkA[i] = mk;
  }
  float acc[8] = {};
  const float* upb = up + (size_t)b * HWP * CCH;
  for (int k = 0; k < 9; ++k) {
    __syncthreads();  // also covers syA/smp reuse hazards
    // --- sample phase: thread t = channel c, all 8 pixels ---
    int c = t;
    int g = t >> 5;
#pragma unroll
    for (int p = 0; p < 8; ++p) {
      int idx = p * 72 + g * 9 + k;
      float sy = syA[idx], sx = sxA[idx], mk = mkA[idx];
      float y0f = floorf(sy), x0f = floorf(sx);
      float fy = sy - y0f, fx = sx - x0f;
      int y0 = (int)y0f, x0 = (int)x0f;
      int y1 = y0 + 1, x1 = x0 + 1;
      bool vy0 = (y0 >= 0) && (y0 <= 63);
      bool vy1 = (y1 >= 0) && (y1 <= 63);
      bool vx0 = (x0 >= 0) && (x0 <= 63);
      bool vx1 = (x1 >= 0) && (x1 <= 63);
      int yc0 = min(max(y0, 0), 63), yc1 = min(max(y1, 0), 63);
      int xc0 = min(max(x0, 0), 63), xc1 = min(max(x1, 0), 63);
      float v00 = (vy0 && vx0) ? upb[((size_t)yc0 * 64 + xc0) * 256 + c] : 0.f;
      float v01 = (vy0 && vx1) ? upb[((size_t)yc0 * 64 + xc1) * 256 + c] : 0.f;
      float v10 = (vy1 && vx0) ? upb[((size_t)yc1 * 64 + xc0) * 256 + c] : 0.f;
      float v11 = (vy1 && vx1) ? upb[((size_t)yc1 * 64 + xc1) * 256 + c] : 0.f;
      float top = v00 + (v01 - v00) * fx;
      float bot = v10 + (v11 - v10) * fx;
      smp[c * 12 + p] = (top + (bot - top) * fy) * mk;
    }
    __syncthreads();
    // --- gemm phase: thread t = output channel f ---
    const float* wk = w_dcn + (size_t)k * 256 * 256 + t;
    for (int cc = 0; cc < 256; ++cc) {
      float wv = wk[(size_t)cc * 256];
      float4 s0 = *(const float4*)&smp[cc * 12];
      float4 s1 = *(const float4*)&smp[cc * 12 + 4];
      acc[0] += s0.x * wv; acc[1] += s0.y * wv;
      acc[2] += s0.z * wv; acc[3] += s0.w * wv;
      acc[4] += s1.x * wv; acc[5] += s1.y * wv;
      acc[6] += s1.z * wv; acc[7] += s1.w * wv;
    }
  }
  float bias = b_dcn[t];
#pragma unroll
  for (int p = 0; p < 8; ++p) {
    float v = fmaxf(acc[p] + bias, 0.f);
    outp[(size_t)(m0 + p) * 256 + t] = v + finecal[(size_t)(m0 + p) * 256 + t];
  }
}

// ---------------------------------------------------------------------------
extern "C" void kernel_launch(void* const* d_in, const int* in_sizes, int n_in,
                              void* d_out, int out_size, void* d_ws, size_t ws_size,
                              hipStream_t stream) {
  const float* coarse = (const float*)d_in[0];
  const float* fine   = (const float*)d_in[1];
  const float* w_att  = (const float*)d_in[2];
  const float* w_sel  = (const float*)d_in[3];
  const float* w_off  = (const float*)d_in[4];
  const float* w_om   = (const float*)d_in[5];
  const float* b_om   = (const float*)d_in[6];
  const float* w_dcn  = (const float*)d_in[7];
  const float* b_dcn  = (const float*)d_in[8];
  float* outp = (float*)d_out;

  float* ws      = (float*)d_ws;
  float* scale   = ws;                   // 1,024 floats
  float* up      = ws + 4096;            // 4,194,304
  float* finecal = up + 4194304;         // 4,194,304
  float* alignb  = finecal + 4194304;    // 8,388,608
  float* omb     = alignb + 8388608;     // 3,538,944  (total ~81.3 MB)

  pool_attn_kernel<<<dim3(4), dim3(1024), 0, stream>>>(fine, w_att, scale);
  upsample_kernel<<<dim3(16384), dim3(256), 0, stream>>>(coarse, up);
  gemm_finecal<<<dim3(4, 256), dim3(256), 0, stream>>>(fine, scale, w_sel, finecal);
  gemm_align<<<dim3(8, 256), dim3(256), 0, stream>>>(finecal, up, w_off, alignb);
  om_conv_kernel<<<dim3(1024), dim3(256), 0, stream>>>(alignb, w_om, b_om, omb);
  dcn_kernel<<<dim3(2048), dim3(256), 0, stream>>>(omb, up, w_dcn, b_dcn, finecal, outp);
}

// Round 2
// 971.373 us; speedup vs baseline: 1.8048x; 1.8048x over previous
//
#include <hip/hip_runtime.h>
#include <hip/hip_bf16.h>
#include <cstddef>

// Shapes (fixed): B=4, H=W=64, C=256, G=8, K=9.
constexpr int HWP  = 64 * 64;  // 4096 pixels per image
constexpr int CCH  = 256;
constexpr int OMC  = 216;      // G*3*K

typedef __attribute__((ext_vector_type(8))) short bf16x8;
typedef __attribute__((ext_vector_type(4))) float f32x4;

__device__ inline unsigned short f2bf(float x) {
  __hip_bfloat16 h = __float2bfloat16(x);
  return *reinterpret_cast<unsigned short*>(&h);
}

// ---------------------------------------------------------------------------
// prep: w_offT[n=512][k=512] bf16 ; w_omT[tap=9][n=224(pad)][c=512] bf16
// ---------------------------------------------------------------------------
__global__ __launch_bounds__(256) void prep_weights(
    const float* __restrict__ w_off, const float* __restrict__ w_om,
    unsigned short* __restrict__ w_offT, unsigned short* __restrict__ w_omT) {
  int i = blockIdx.x * 256 + threadIdx.x;
  if (i < 512 * 512) {
    int n = i >> 9, k = i & 511;
    w_offT[i] = f2bf(w_off[k * 512 + n]);
  }
  if (i < 9 * 224 * 512) {
    int c = i & 511;
    int r = i >> 9;            // tap*224 + n
    int tap = r / 224;
    int n = r - tap * 224;
    w_omT[i] = f2bf(n < OMC ? w_om[((size_t)tap * 512 + c) * OMC + n] : 0.f);
  }
}

// ---------------------------------------------------------------------------
// Stage 1: pooled mean -> attn sigmoid -> scale = attn+1
// ---------------------------------------------------------------------------
__global__ __launch_bounds__(1024) void pool_attn_kernel(
    const float* __restrict__ fine, const float* __restrict__ w_att,
    float* __restrict__ scale) {
  __shared__ float red[1024];
  __shared__ float pl[256];
  int b = blockIdx.x;
  int t = threadIdx.x;
  int c = t & 255;
  int chunk = t >> 8;
  const float* src = fine + (size_t)b * HWP * CCH;
  float s = 0.f;
  for (int p = chunk * 1024; p < chunk * 1024 + 1024; ++p)
    s += src[(size_t)p * CCH + c];
  red[t] = s;
  __syncthreads();
  if (t < 256)
    pl[t] = (red[t] + red[t + 256] + red[t + 512] + red[t + 768]) * (1.0f / 4096.0f);
  __syncthreads();
  if (t < 256) {
    float acc = 0.f;
    for (int ci = 0; ci < 256; ++ci)
      acc += pl[ci] * w_att[ci * 256 + t];
    scale[b * 256 + t] = 1.0f + 1.0f / (1.0f + expf(-acc));
  }
}

// ---------------------------------------------------------------------------
// Stage 2: bilinear upsample 32->64 (fp32 `up` for dcn sampling) and
//          bf16 2*up into alignA cols 256..511
// ---------------------------------------------------------------------------
__global__ __launch_bounds__(256) void upsample_kernel(
    const float* __restrict__ coarse, float* __restrict__ up,
    unsigned short* __restrict__ alignA) {
  int m = blockIdx.x;  // b*4096 + h*64 + w
  int c = threadIdx.x;
  int b = m >> 12, h = (m >> 6) & 63, w = m & 63;
  float cy = fminf(fmaxf(h * 0.5f - 0.25f, 0.f), 31.f);
  float cx = fminf(fmaxf(w * 0.5f - 0.25f, 0.f), 31.f);
  int y0 = (int)cy, x0 = (int)cx;
  float fy = cy - y0, fx = cx - x0;
  int y1 = min(y0 + 1, 31), x1 = min(x0 + 1, 31);
  const float* base = coarse + (size_t)b * 32 * 32 * CCH;
  float v00 = base[(y0 * 32 + x0) * CCH + c];
  float v01 = base[(y0 * 32 + x1) * CCH + c];
  float v10 = base[(y1 * 32 + x0) * CCH + c];
  float v11 = base[(y1 * 32 + x1) * CCH + c];
  float top = v00 + (v01 - v00) * fx;
  float bot = v10 + (v11 - v10) * fx;
  float v = top + (bot - top) * fy;
  up[(size_t)m * CCH + c] = v;
  alignA[(size_t)m * 512 + 256 + c] = f2bf(2.f * v);
}

// ---------------------------------------------------------------------------
// Stage 3: fine_cal = (fine*scale) @ w_sel  (fp32 out for residual,
//          bf16 copy into alignA cols 0..255)
// ---------------------------------------------------------------------------
__global__ __launch_bounds__(256) void gemm_finecal(
    const float* __restrict__ fine, const float* __restrict__ scale,
    const float* __restrict__ w_sel, float* __restrict__ outp,
    unsigned short* __restrict__ alignA) {
  __shared__ float As[16][68];
  __shared__ float Bs[16][64];
  int n0 = blockIdx.x * 64;
  int m0 = blockIdx.y * 64;
  int t = threadIdx.x, tx = t & 15, ty = t >> 4;
  int bb = m0 >> 12;
  float acc[4][4] = {};
  for (int k0 = 0; k0 < 256; k0 += 16) {
    for (int i = t; i < 64 * 16; i += 256) {
      int kk = i & 15, row = i >> 4;
      As[kk][row] = fine[(size_t)(m0 + row) * 256 + k0 + kk] * scale[bb * 256 + k0 + kk];
    }
    for (int i = t; i < 16 * 64; i += 256) {
      int col = i & 63, kk = i >> 6;
      Bs[kk][col] = w_sel[(size_t)(k0 + kk) * 256 + n0 + col];
    }
    __syncthreads();
#pragma unroll
    for (int kk = 0; kk < 16; ++kk) {
      float4 a4 = *(const float4*)&As[kk][ty * 4];
      float4 b4 = *(const float4*)&Bs[kk][tx * 4];
      float av[4] = {a4.x, a4.y, a4.z, a4.w};
      float bv[4] = {b4.x, b4.y, b4.z, b4.w};
#pragma unroll
      for (int i = 0; i < 4; ++i)
#pragma unroll
        for (int j = 0; j < 4; ++j) acc[i][j] += av[i] * bv[j];
    }
    __syncthreads();
  }
#pragma unroll
  for (int i = 0; i < 4; ++i) {
    int m = m0 + ty * 4 + i;
    float4 v = make_float4(acc[i][0], acc[i][1], acc[i][2], acc[i][3]);
    *(float4*)&outp[(size_t)m * 256 + n0 + tx * 4] = v;
    ushort4 u = make_ushort4(f2bf(acc[i][0]), f2bf(acc[i][1]),
                             f2bf(acc[i][2]), f2bf(acc[i][3]));
    *(ushort4*)&alignA[(size_t)m * 512 + n0 + tx * 4] = u;
  }
}

// ---------------------------------------------------------------------------
// Stage 4 (MFMA): align = alignA @ w_off  -> bf16 [16384][512]
// Tile M=128 N=64 BK=64; 4 waves, wave = 32 rows x 64 cols.
// ---------------------------------------------------------------------------
__global__ __launch_bounds__(256) void gemm_align_mfma(
    const unsigned short* __restrict__ alignA,   // [16384][512] bf16
    const unsigned short* __restrict__ w_offT,   // [512 n][512 k] bf16
    unsigned short* __restrict__ alignBf) {      // [16384][512] bf16
  __shared__ unsigned short As[128][72];
  __shared__ unsigned short Bs[64][72];
  int n0 = blockIdx.x * 64;
  int m0 = blockIdx.y * 128;
  int t = threadIdx.x;
  int wid = t >> 6, lane = t & 63;
  int lrow = lane & 15, lq = lane >> 4;
  f32x4 acc[2][4];
#pragma unroll
  for (int i = 0; i < 2; ++i)
#pragma unroll
    for (int j = 0; j < 4; ++j) acc[i][j] = (f32x4){0.f, 0.f, 0.f, 0.f};
  for (int k0 = 0; k0 < 512; k0 += 64) {
    __syncthreads();
    for (int u = t; u < 128 * 8; u += 256) {
      int row = u >> 3, ck = u & 7;
      *(uint4*)&As[row][ck * 8] =
          *(const uint4*)&alignA[(size_t)(m0 + row) * 512 + k0 + ck * 8];
    }
    for (int u = t; u < 64 * 8; u += 256) {
      int row = u >> 3, ck = u & 7;
      *(uint4*)&Bs[row][ck * 8] =
          *(const uint4*)&w_offT[(size_t)(n0 + row) * 512 + k0 + ck * 8];
    }
    __syncthreads();
#pragma unroll
    for (int kk = 0; kk < 2; ++kk) {
      bf16x8 a[2], b[4];
#pragma unroll
      for (int mt = 0; mt < 2; ++mt)
        a[mt] = *(const bf16x8*)&As[wid * 32 + mt * 16 + lrow][kk * 32 + lq * 8];
#pragma unroll
      for (int nt = 0; nt < 4; ++nt)
        b[nt] = *(const bf16x8*)&Bs[nt * 16 + lrow][kk * 32 + lq * 8];
#pragma unroll
      for (int mt = 0; mt < 2; ++mt)
#pragma unroll
        for (int nt = 0; nt < 4; ++nt)
          acc[mt][nt] = __builtin_amdgcn_mfma_f32_16x16x32_bf16(
              a[mt], b[nt], acc[mt][nt], 0, 0, 0);
    }
  }
  // C layout: col = lane&15, row = (lane>>4)*4 + reg
#pragma unroll
  for (int mt = 0; mt < 2; ++mt)
#pragma unroll
    for (int nt = 0; nt < 4; ++nt)
#pragma unroll
      for (int r = 0; r < 4; ++r) {
        int m = m0 + wid * 32 + mt * 16 + lq * 4 + r;
        int n = n0 + nt * 16 + lrow;
        alignBf[(size_t)m * 512 + n] = f2bf(acc[mt][nt][r]);
      }
}

// ---------------------------------------------------------------------------
// Stage 5 (MFMA): om = conv3x3(align) + b_om  as 9 shifted GEMMs.
// Block = one image row (64 px) x half of N (112 of 224-padded).
// A_ext[3 dy][66 px][64 ch] staged per 64-ch chunk; B per (tap, chunk).
// ---------------------------------------------------------------------------
__global__ __launch_bounds__(256) void om_conv_mfma(
    const unsigned short* __restrict__ alignBf,  // [16384][512] bf16
    const unsigned short* __restrict__ w_omT,    // [9][224][512] bf16
    const float* __restrict__ b_om,
    float* __restrict__ om) {                    // [16384][216] fp32
  __shared__ unsigned short As[3][66][72];
  __shared__ unsigned short Bs[112][72];
  int bh = blockIdx.x;            // b*64 + h
  int nhalf = blockIdx.y;         // 0/1 -> n base 0/112
  int h = bh & 63;
  int t = threadIdx.x;
  int wid = t >> 6, lane = t & 63;
  int lrow = lane & 15, lq = lane >> 4;
  f32x4 acc[7];
#pragma unroll
  for (int j = 0; j < 7; ++j) acc[j] = (f32x4){0.f, 0.f, 0.f, 0.f};
  for (int c0 = 0; c0 < 512; c0 += 64) {
    __syncthreads();  // prior-iteration MFMAs done before As overwrite
    for (int u = t; u < 3 * 66 * 8; u += 256) {
      int dy = u / 528;
      int r = u - dy * 528;
      int px = r >> 3, ck = r & 7;
      int w = px - 1;
      int y = h + dy - 1;
      uint4 v = make_uint4(0u, 0u, 0u, 0u);
      if (w >= 0 && w < 64 && y >= 0 && y < 64)
        v = *(const uint4*)&alignBf[((size_t)(bh + dy - 1) * 64 + w) * 512 + c0 + ck * 8];
      *(uint4*)&As[dy][px][ck * 8] = v;
    }
    for (int tap = 0; tap < 9; ++tap) {
      __syncthreads();  // As staged / prior Bs consumers done
      for (int u = t; u < 112 * 8; u += 256) {
        int n = u >> 3, ck = u & 7;
        *(uint4*)&Bs[n][ck * 8] =
            *(const uint4*)&w_omT[((size_t)tap * 224 + nhalf * 112 + n) * 512 + c0 + ck * 8];
      }
      __syncthreads();
      int dyt = tap / 3, dxt = tap - dyt * 3;
#pragma unroll
      for (int kk = 0; kk < 2; ++kk) {
        bf16x8 a = *(const bf16x8*)&As[dyt][wid * 16 + lrow + dxt][kk * 32 + lq * 8];
#pragma unroll
        for (int nt = 0; nt < 7; ++nt) {
          bf16x8 b = *(const bf16x8*)&Bs[nt * 16 + lrow][kk * 32 + lq * 8];
          acc[nt] = __builtin_amdgcn_mfma_f32_16x16x32_bf16(a, b, acc[nt], 0, 0, 0);
        }
      }
    }
  }
#pragma unroll
  for (int nt = 0; nt < 7; ++nt) {
    int n = nhalf * 112 + nt * 16 + lrow;
    if (n < OMC) {
      float bias = b_om[n];
#pragma unroll
      for (int r = 0; r < 4; ++r) {
        int m = bh * 64 + wid * 16 + lq * 4 + r;
        om[(size_t)m * OMC + n] = acc[nt][r] + bias;
      }
    }
  }
}

// ---------------------------------------------------------------------------
// Stage 6: deformable sample + einsum + bias + relu + residual (fp32)
// ---------------------------------------------------------------------------
__global__ __launch_bounds__(256) void dcn_kernel(
    const float* __restrict__ om, const float* __restrict__ up,
    const float* __restrict__ w_dcn, const float* __restrict__ b_dcn,
    const float* __restrict__ finecal, float* __restrict__ outp) {
  __shared__ float syA[576], sxA[576], mkA[576];  // [p][g][k] : 8*8*9
  __shared__ float smp[256 * 12];                 // [c][p], stride 12
  int blk = blockIdx.x;
  int m0 = blk * 8;
  int b = m0 >> 12;
  int h = (m0 >> 6) & 63;
  int w0 = m0 & 63;
  int t = threadIdx.x;
  for (int i = t; i < 576; i += 256) {
    int p = i / 72;
    int r = i - p * 72;
    int g = r / 9;
    int k = r - g * 9;
    const float* omr = om + (size_t)(m0 + p) * OMC;
    float dy = omr[g * 18 + k * 2];
    float dx = omr[g * 18 + k * 2 + 1];
    float mk = 1.0f / (1.0f + expf(-omr[144 + g * 9 + k]));
    int ky = k / 3;
    int kx = k - ky * 3;
    syA[i] = (float)(h + ky - 1) + dy;
    sxA[i] = (float)(w0 + p + kx - 1) + dx;
    mkA[i] = mk;
  }
  float acc[8] = {};
  const float* upb = up + (size_t)b * HWP * CCH;
  for (int k = 0; k < 9; ++k) {
    __syncthreads();
    int c = t;
    int g = t >> 5;
#pragma unroll
    for (int p = 0; p < 8; ++p) {
      int idx = p * 72 + g * 9 + k;
      float sy = syA[idx], sx = sxA[idx], mk = mkA[idx];
      float y0f = floorf(sy), x0f = floorf(sx);
      float fy = sy - y0f, fx = sx - x0f;
      int y0 = (int)y0f, x0 = (int)x0f;
      int y1 = y0 + 1, x1 = x0 + 1;
      bool vy0 = (y0 >= 0) && (y0 <= 63);
      bool vy1 = (y1 >= 0) && (y1 <= 63);
      bool vx0 = (x0 >= 0) && (x0 <= 63);
      bool vx1 = (x1 >= 0) && (x1 <= 63);
      int yc0 = min(max(y0, 0), 63), yc1 = min(max(y1, 0), 63);
      int xc0 = min(max(x0, 0), 63), xc1 = min(max(x1, 0), 63);
      float v00 = (vy0 && vx0) ? upb[((size_t)yc0 * 64 + xc0) * 256 + c] : 0.f;
      float v01 = (vy0 && vx1) ? upb[((size_t)yc0 * 64 + xc1) * 256 + c] : 0.f;
      float v10 = (vy1 && vx0) ? upb[((size_t)yc1 * 64 + xc0) * 256 + c] : 0.f;
      float v11 = (vy1 && vx1) ? upb[((size_t)yc1 * 64 + xc1) * 256 + c] : 0.f;
      float top = v00 + (v01 - v00) * fx;
      float bot = v10 + (v11 - v10) * fx;
      smp[c * 12 + p] = (top + (bot - top) * fy) * mk;
    }
    __syncthreads();
    const float* wk = w_dcn + (size_t)k * 256 * 256 + t;
    for (int cc = 0; cc < 256; ++cc) {
      float wv = wk[(size_t)cc * 256];
      float4 s0 = *(const float4*)&smp[cc * 12];
      float4 s1 = *(const float4*)&smp[cc * 12 + 4];
      acc[0] += s0.x * wv; acc[1] += s0.y * wv;
      acc[2] += s0.z * wv; acc[3] += s0.w * wv;
      acc[4] += s1.x * wv; acc[5] += s1.y * wv;
      acc[6] += s1.z * wv; acc[7] += s1.w * wv;
    }
  }
  float bias = b_dcn[t];
#pragma unroll
  for (int p = 0; p < 8; ++p) {
    float v = fmaxf(acc[p] + bias, 0.f);
    outp[(size_t)(m0 + p) * 256 + t] = v + finecal[(size_t)(m0 + p) * 256 + t];
  }
}

// ---------------------------------------------------------------------------
extern "C" void kernel_launch(void* const* d_in, const int* in_sizes, int n_in,
                              void* d_out, int out_size, void* d_ws, size_t ws_size,
                              hipStream_t stream) {
  const float* coarse = (const float*)d_in[0];
  const float* fine   = (const float*)d_in[1];
  const float* w_att  = (const float*)d_in[2];
  const float* w_sel  = (const float*)d_in[3];
  const float* w_off  = (const float*)d_in[4];
  const float* w_om   = (const float*)d_in[5];
  const float* b_om   = (const float*)d_in[6];
  const float* w_dcn  = (const float*)d_in[7];
  const float* b_dcn  = (const float*)d_in[8];
  float* outp = (float*)d_out;

  char* base = (char*)d_ws;
  size_t o = 0;
  float* scale            = (float*)(base + o);          o += 4096;
  float* up               = (float*)(base + o);          o += 16777216;
  float* finecal          = (float*)(base + o);          o += 16777216;
  float* omb              = (float*)(base + o);          o += 14155776;
  unsigned short* alignA  = (unsigned short*)(base + o); o += 16777216;
  unsigned short* alignBf = (unsigned short*)(base + o); o += 16777216;
  unsigned short* w_offT  = (unsigned short*)(base + o); o += 524288;
  unsigned short* w_omT   = (unsigned short*)(base + o); o += 2064384;
  // total ~83.9 MB

  prep_weights<<<dim3(4032), dim3(256), 0, stream>>>(w_off, w_om, w_offT, w_omT);
  pool_attn_kernel<<<dim3(4), dim3(1024), 0, stream>>>(fine, w_att, scale);
  upsample_kernel<<<dim3(16384), dim3(256), 0, stream>>>(coarse, up, alignA);
  gemm_finecal<<<dim3(4, 256), dim3(256), 0, stream>>>(fine, scale, w_sel, finecal, alignA);
  gemm_align_mfma<<<dim3(8, 128), dim3(256), 0, stream>>>(alignA, w_offT, alignBf);
  om_conv_mfma<<<dim3(256, 2), dim3(256), 0, stream>>>(alignBf, w_omT, b_om, omb);
  dcn_kernel<<<dim3(2048), dim3(256), 0, stream>>>(omb, up, w_dcn, b_dcn, finecal, outp);
}

// Round 3
// 615.281 us; speedup vs baseline: 2.8493x; 1.5787x over previous
//
#include <hip/hip_runtime.h>
#include <hip/hip_bf16.h>
#include <cstddef>

// Shapes (fixed): B=4, H=W=64, C=256, G=8, K=9.
constexpr int HWP  = 64 * 64;  // 4096 pixels per image
constexpr int CCH  = 256;
constexpr int OMC  = 216;      // G*3*K

typedef __attribute__((ext_vector_type(8))) short bf16x8;
typedef __attribute__((ext_vector_type(4))) float f32x4;

__device__ inline unsigned short f2bf(float x) {
  __hip_bfloat16 h = __float2bfloat16(x);
  return *reinterpret_cast<unsigned short*>(&h);
}

// ---------------------------------------------------------------------------
// prep: w_offT[n=512][k=512] bf16 ; w_omT[tap=9][n=224(pad)][c=512] bf16 ;
//       w_dcnT[tap=9][f=256][c=256] bf16
// ---------------------------------------------------------------------------
__global__ __launch_bounds__(256) void prep_weights(
    const float* __restrict__ w_off, const float* __restrict__ w_om,
    const float* __restrict__ w_dcn,
    unsigned short* __restrict__ w_offT, unsigned short* __restrict__ w_omT,
    unsigned short* __restrict__ w_dcnT) {
  int i = blockIdx.x * 256 + threadIdx.x;
  if (i < 512 * 512) {
    int n = i >> 9, k = i & 511;
    w_offT[i] = f2bf(w_off[k * 512 + n]);
  }
  if (i < 9 * 224 * 512) {
    int c = i & 511;
    int r = i >> 9;            // tap*224 + n
    int tap = r / 224;
    int n = r - tap * 224;
    w_omT[i] = f2bf(n < OMC ? w_om[((size_t)tap * 512 + c) * OMC + n] : 0.f);
  }
  if (i < 9 * 256 * 256) {
    int tap = i >> 16, f = (i >> 8) & 255, c = i & 255;
    w_dcnT[i] = f2bf(w_dcn[((size_t)tap * 256 + c) * 256 + f]);
  }
}

// ---------------------------------------------------------------------------
// Stage 1a: partial pooling — block (r, b) sums 64 pixels per channel
// ---------------------------------------------------------------------------
__global__ __launch_bounds__(256) void pool_partial(
    const float* __restrict__ fine, float* __restrict__ partial) {
  int r = blockIdx.x;  // 0..63
  int b = blockIdx.y;  // 0..3
  int t = threadIdx.x;
  const float* src = fine + ((size_t)b * 4096 + r * 64) * 256 + t;
  float s = 0.f;
#pragma unroll 8
  for (int p = 0; p < 64; ++p) s += src[(size_t)p * 256];
  partial[((size_t)b * 64 + r) * 256 + t] = s;
}

// ---------------------------------------------------------------------------
// Stage 1b: finish pooling + attn matvec + sigmoid ; scale = attn+1
// ---------------------------------------------------------------------------
__global__ __launch_bounds__(256) void pool_finish(
    const float* __restrict__ partial, const float* __restrict__ w_att,
    float* __restrict__ scale) {
  __shared__ float pl[256];
  int b = blockIdx.x;
  int t = threadIdx.x;
  const float* pp = partial + (size_t)b * 64 * 256 + t;
  float s = 0.f;
#pragma unroll 8
  for (int r = 0; r < 64; ++r) s += pp[(size_t)r * 256];
  pl[t] = s * (1.0f / 4096.0f);
  __syncthreads();
  float acc = 0.f;
  for (int ci = 0; ci < 256; ++ci) acc += pl[ci] * w_att[ci * 256 + t];
  scale[b * 256 + t] = 1.0f + 1.0f / (1.0f + expf(-acc));
}

// ---------------------------------------------------------------------------
// Stage 2: bilinear upsample 32->64 (fp32 `up` for dcn sampling) and
//          bf16 2*up into alignA cols 256..511
// ---------------------------------------------------------------------------
__global__ __launch_bounds__(256) void upsample_kernel(
    const float* __restrict__ coarse, float* __restrict__ up,
    unsigned short* __restrict__ alignA) {
  int m = blockIdx.x;  // b*4096 + h*64 + w
  int c = threadIdx.x;
  int b = m >> 12, h = (m >> 6) & 63, w = m & 63;
  float cy = fminf(fmaxf(h * 0.5f - 0.25f, 0.f), 31.f);
  float cx = fminf(fmaxf(w * 0.5f - 0.25f, 0.f), 31.f);
  int y0 = (int)cy, x0 = (int)cx;
  float fy = cy - y0, fx = cx - x0;
  int y1 = min(y0 + 1, 31), x1 = min(x0 + 1, 31);
  const float* base = coarse + (size_t)b * 32 * 32 * CCH;
  float v00 = base[(y0 * 32 + x0) * CCH + c];
  float v01 = base[(y0 * 32 + x1) * CCH + c];
  float v10 = base[(y1 * 32 + x0) * CCH + c];
  float v11 = base[(y1 * 32 + x1) * CCH + c];
  float top = v00 + (v01 - v00) * fx;
  float bot = v10 + (v11 - v10) * fx;
  float v = top + (bot - top) * fy;
  up[(size_t)m * CCH + c] = v;
  alignA[(size_t)m * 512 + 256 + c] = f2bf(2.f * v);
}

// ---------------------------------------------------------------------------
// Stage 3: fine_cal = (fine*scale) @ w_sel  (fp32 out for residual,
//          bf16 copy into alignA cols 0..255)
// ---------------------------------------------------------------------------
__global__ __launch_bounds__(256) void gemm_finecal(
    const float* __restrict__ fine, const float* __restrict__ scale,
    const float* __restrict__ w_sel, float* __restrict__ outp,
    unsigned short* __restrict__ alignA) {
  __shared__ float As[16][68];
  __shared__ float Bs[16][64];
  int n0 = blockIdx.x * 64;
  int m0 = blockIdx.y * 64;
  int t = threadIdx.x, tx = t & 15, ty = t >> 4;
  int bb = m0 >> 12;
  float acc[4][4] = {};
  for (int k0 = 0; k0 < 256; k0 += 16) {
    for (int i = t; i < 64 * 16; i += 256) {
      int kk = i & 15, row = i >> 4;
      As[kk][row] = fine[(size_t)(m0 + row) * 256 + k0 + kk] * scale[bb * 256 + k0 + kk];
    }
    for (int i = t; i < 16 * 64; i += 256) {
      int col = i & 63, kk = i >> 6;
      Bs[kk][col] = w_sel[(size_t)(k0 + kk) * 256 + n0 + col];
    }
    __syncthreads();
#pragma unroll
    for (int kk = 0; kk < 16; ++kk) {
      float4 a4 = *(const float4*)&As[kk][ty * 4];
      float4 b4 = *(const float4*)&Bs[kk][tx * 4];
      float av[4] = {a4.x, a4.y, a4.z, a4.w};
      float bv[4] = {b4.x, b4.y, b4.z, b4.w};
#pragma unroll
      for (int i = 0; i < 4; ++i)
#pragma unroll
        for (int j = 0; j < 4; ++j) acc[i][j] += av[i] * bv[j];
    }
    __syncthreads();
  }
#pragma unroll
  for (int i = 0; i < 4; ++i) {
    int m = m0 + ty * 4 + i;
    float4 v = make_float4(acc[i][0], acc[i][1], acc[i][2], acc[i][3]);
    *(float4*)&outp[(size_t)m * 256 + n0 + tx * 4] = v;
    ushort4 u = make_ushort4(f2bf(acc[i][0]), f2bf(acc[i][1]),
                             f2bf(acc[i][2]), f2bf(acc[i][3]));
    *(ushort4*)&alignA[(size_t)m * 512 + n0 + tx * 4] = u;
  }
}

// ---------------------------------------------------------------------------
// Stage 4 (MFMA): align = alignA @ w_off  -> bf16 [16384][512]
// ---------------------------------------------------------------------------
__global__ __launch_bounds__(256) void gemm_align_mfma(
    const unsigned short* __restrict__ alignA,   // [16384][512] bf16
    const unsigned short* __restrict__ w_offT,   // [512 n][512 k] bf16
    unsigned short* __restrict__ alignBf) {      // [16384][512] bf16
  __shared__ unsigned short As[128][72];
  __shared__ unsigned short Bs[64][72];
  int n0 = blockIdx.x * 64;
  int m0 = blockIdx.y * 128;
  int t = threadIdx.x;
  int wid = t >> 6, lane = t & 63;
  int lrow = lane & 15, lq = lane >> 4;
  f32x4 acc[2][4];
#pragma unroll
  for (int i = 0; i < 2; ++i)
#pragma unroll
    for (int j = 0; j < 4; ++j) acc[i][j] = (f32x4){0.f, 0.f, 0.f, 0.f};
  for (int k0 = 0; k0 < 512; k0 += 64) {
    __syncthreads();
    for (int u = t; u < 128 * 8; u += 256) {
      int row = u >> 3, ck = u & 7;
      *(uint4*)&As[row][ck * 8] =
          *(const uint4*)&alignA[(size_t)(m0 + row) * 512 + k0 + ck * 8];
    }
    for (int u = t; u < 64 * 8; u += 256) {
      int row = u >> 3, ck = u & 7;
      *(uint4*)&Bs[row][ck * 8] =
          *(const uint4*)&w_offT[(size_t)(n0 + row) * 512 + k0 + ck * 8];
    }
    __syncthreads();
#pragma unroll
    for (int kk = 0; kk < 2; ++kk) {
      bf16x8 a[2], b[4];
#pragma unroll
      for (int mt = 0; mt < 2; ++mt)
        a[mt] = *(const bf16x8*)&As[wid * 32 + mt * 16 + lrow][kk * 32 + lq * 8];
#pragma unroll
      for (int nt = 0; nt < 4; ++nt)
        b[nt] = *(const bf16x8*)&Bs[nt * 16 + lrow][kk * 32 + lq * 8];
#pragma unroll
      for (int mt = 0; mt < 2; ++mt)
#pragma unroll
        for (int nt = 0; nt < 4; ++nt)
          acc[mt][nt] = __builtin_amdgcn_mfma_f32_16x16x32_bf16(
              a[mt], b[nt], acc[mt][nt], 0, 0, 0);
    }
  }
#pragma unroll
  for (int mt = 0; mt < 2; ++mt)
#pragma unroll
    for (int nt = 0; nt < 4; ++nt)
#pragma unroll
      for (int r = 0; r < 4; ++r) {
        int m = m0 + wid * 32 + mt * 16 + lq * 4 + r;
        int n = n0 + nt * 16 + lrow;
        alignBf[(size_t)m * 512 + n] = f2bf(acc[mt][nt][r]);
      }
}

// ---------------------------------------------------------------------------
// Stage 5 (MFMA): om = conv3x3(align) + b_om  as 9 shifted GEMMs.
// ---------------------------------------------------------------------------
__global__ __launch_bounds__(256) void om_conv_mfma(
    const unsigned short* __restrict__ alignBf,  // [16384][512] bf16
    const unsigned short* __restrict__ w_omT,    // [9][224][512] bf16
    const float* __restrict__ b_om,
    float* __restrict__ om) {                    // [16384][216] fp32
  __shared__ unsigned short As[3][66][72];
  __shared__ unsigned short Bs[112][72];
  int bh = blockIdx.x;            // b*64 + h
  int nhalf = blockIdx.y;         // 0/1 -> n base 0/112
  int h = bh & 63;
  int t = threadIdx.x;
  int wid = t >> 6, lane = t & 63;
  int lrow = lane & 15, lq = lane >> 4;
  f32x4 acc[7];
#pragma unroll
  for (int j = 0; j < 7; ++j) acc[j] = (f32x4){0.f, 0.f, 0.f, 0.f};
  for (int c0 = 0; c0 < 512; c0 += 64) {
    __syncthreads();
    for (int u = t; u < 3 * 66 * 8; u += 256) {
      int dy = u / 528;
      int r = u - dy * 528;
      int px = r >> 3, ck = r & 7;
      int w = px - 1;
      int y = h + dy - 1;
      uint4 v = make_uint4(0u, 0u, 0u, 0u);
      if (w >= 0 && w < 64 && y >= 0 && y < 64)
        v = *(const uint4*)&alignBf[((size_t)(bh + dy - 1) * 64 + w) * 512 + c0 + ck * 8];
      *(uint4*)&As[dy][px][ck * 8] = v;
    }
    for (int tap = 0; tap < 9; ++tap) {
      __syncthreads();
      for (int u = t; u < 112 * 8; u += 256) {
        int n = u >> 3, ck = u & 7;
        *(uint4*)&Bs[n][ck * 8] =
            *(const uint4*)&w_omT[((size_t)tap * 224 + nhalf * 112 + n) * 512 + c0 + ck * 8];
      }
      __syncthreads();
      int dyt = tap / 3, dxt = tap - dyt * 3;
#pragma unroll
      for (int kk = 0; kk < 2; ++kk) {
        bf16x8 a = *(const bf16x8*)&As[dyt][wid * 16 + lrow + dxt][kk * 32 + lq * 8];
#pragma unroll
        for (int nt = 0; nt < 7; ++nt) {
          bf16x8 b = *(const bf16x8*)&Bs[nt * 16 + lrow][kk * 32 + lq * 8];
          acc[nt] = __builtin_amdgcn_mfma_f32_16x16x32_bf16(a, b, acc[nt], 0, 0, 0);
        }
      }
    }
  }
#pragma unroll
  for (int nt = 0; nt < 7; ++nt) {
    int n = nhalf * 112 + nt * 16 + lrow;
    if (n < OMC) {
      float bias = b_om[n];
#pragma unroll
      for (int r = 0; r < 4; ++r) {
        int m = bh * 64 + wid * 16 + lq * 4 + r;
        om[(size_t)m * OMC + n] = acc[nt][r] + bias;
      }
    }
  }
}

// ---------------------------------------------------------------------------
// Stage 6 (MFMA): deformable sample (bf16) + einsum + bias + relu + residual
// Block = one image row (64 px). Per tap: stage offsets/weights -> sample
// 64x256 bf16 tile -> 8 MFMA k-steps. Wave (mi,ni): m 32, n 128.
// ---------------------------------------------------------------------------
__global__ __launch_bounds__(256) void dcn_mfma(
    const float* __restrict__ om, const float* __restrict__ up,
    const unsigned short* __restrict__ w_dcnT,   // [9][256 f][256 c] bf16
    const float* __restrict__ b_dcn,
    const float* __restrict__ finecal, float* __restrict__ outp) {
  __shared__ int offsA[512][4];                  // [p 64][g 8] pixel offsets*256
  __shared__ float wtsA[512][4];                 // bilinear weights * mask
  __shared__ unsigned short smp[64][264];        // sampled tile, bf16, pad 8
  int bh = blockIdx.x;                           // b*64 + h
  int b = bh >> 6, h = bh & 63;
  int m0 = bh * 64;
  int t = threadIdx.x;
  int wid = t >> 6, lane = t & 63;
  int mi = wid >> 1, ni = wid & 1;
  int lrow = lane & 15, lq = lane >> 4;
  f32x4 acc[2][8];
#pragma unroll
  for (int i = 0; i < 2; ++i)
#pragma unroll
    for (int j = 0; j < 8; ++j) acc[i][j] = (f32x4){0.f, 0.f, 0.f, 0.f};
  const float* upb = up + (size_t)b * HWP * CCH;

  for (int tap = 0; tap < 9; ++tap) {
    int ky = tap / 3, kx = tap - ky * 3;
    __syncthreads();  // prior-tap readers of smp/coords done
    // ---- stage offsets + weights: 512 items (64 px x 8 groups) ----
    for (int i = t; i < 512; i += 256) {
      int p = i >> 3, g = i & 7;
      const float* omr = om + (size_t)(m0 + p) * OMC;
      float dy = omr[g * 18 + tap * 2];
      float dx = omr[g * 18 + tap * 2 + 1];
      float mk = 1.0f / (1.0f + expf(-omr[144 + g * 9 + tap]));
      float sy = (float)(h + ky - 1) + dy;
      float sx = (float)(p + kx - 1) + dx;
      float y0f = floorf(sy), x0f = floorf(sx);
      float fy = sy - y0f, fx = sx - x0f;
      int y0 = (int)y0f, x0 = (int)x0f;
      int y1 = y0 + 1, x1 = x0 + 1;
      float vy0 = (y0 >= 0 && y0 <= 63) ? 1.f : 0.f;
      float vy1 = (y1 >= 0 && y1 <= 63) ? 1.f : 0.f;
      float vx0 = (x0 >= 0 && x0 <= 63) ? 1.f : 0.f;
      float vx1 = (x1 >= 0 && x1 <= 63) ? 1.f : 0.f;
      int yc0 = min(max(y0, 0), 63), yc1 = min(max(y1, 0), 63);
      int xc0 = min(max(x0, 0), 63), xc1 = min(max(x1, 0), 63);
      offsA[i][0] = (yc0 * 64 + xc0) * 256;
      offsA[i][1] = (yc0 * 64 + xc1) * 256;
      offsA[i][2] = (yc1 * 64 + xc0) * 256;
      offsA[i][3] = (yc1 * 64 + xc1) * 256;
      wtsA[i][0] = (1.f - fy) * (1.f - fx) * vy0 * vx0 * mk;
      wtsA[i][1] = (1.f - fy) * fx * vy0 * vx1 * mk;
      wtsA[i][2] = fy * (1.f - fx) * vy1 * vx0 * mk;
      wtsA[i][3] = fy * fx * vy1 * vx1 * mk;
    }
    __syncthreads();
    // ---- sample phase: thread = channel, loop over 64 pixels ----
    {
      int c = t, g = t >> 5;
#pragma unroll 4
      for (int p = 0; p < 64; ++p) {
        int idx = (p << 3) | g;
        int4 o = *(const int4*)&offsA[idx][0];
        float4 w = *(const float4*)&wtsA[idx][0];
        float v = w.x * upb[o.x + c] + w.y * upb[o.y + c] +
                  w.z * upb[o.z + c] + w.w * upb[o.w + c];
        smp[p][c] = f2bf(v);
      }
    }
    __syncthreads();
    // ---- MFMA phase: 8 k-steps over 256 channels ----
#pragma unroll
    for (int ks = 0; ks < 8; ++ks) {
      bf16x8 a0 = *(const bf16x8*)&smp[mi * 32 + lrow][ks * 32 + lq * 8];
      bf16x8 a1 = *(const bf16x8*)&smp[mi * 32 + 16 + lrow][ks * 32 + lq * 8];
#pragma unroll
      for (int nt = 0; nt < 8; ++nt) {
        int f = ni * 128 + nt * 16 + lrow;
        bf16x8 bf = *(const bf16x8*)&w_dcnT[((size_t)tap * 256 + f) * 256 + ks * 32 + lq * 8];
        acc[0][nt] = __builtin_amdgcn_mfma_f32_16x16x32_bf16(a0, bf, acc[0][nt], 0, 0, 0);
        acc[1][nt] = __builtin_amdgcn_mfma_f32_16x16x32_bf16(a1, bf, acc[1][nt], 0, 0, 0);
      }
    }
  }
  // ---- epilogue: bias + relu + residual ----
#pragma unroll
  for (int mt = 0; mt < 2; ++mt)
#pragma unroll
    for (int nt = 0; nt < 8; ++nt) {
      int f = ni * 128 + nt * 16 + lrow;
      float bias = b_dcn[f];
#pragma unroll
      for (int r = 0; r < 4; ++r) {
        int m = m0 + mi * 32 + mt * 16 + lq * 4 + r;
        float v = fmaxf(acc[mt][nt][r] + bias, 0.f);
        outp[(size_t)m * 256 + f] = v + finecal[(size_t)m * 256 + f];
      }
    }
}

// ---------------------------------------------------------------------------
extern "C" void kernel_launch(void* const* d_in, const int* in_sizes, int n_in,
                              void* d_out, int out_size, void* d_ws, size_t ws_size,
                              hipStream_t stream) {
  const float* coarse = (const float*)d_in[0];
  const float* fine   = (const float*)d_in[1];
  const float* w_att  = (const float*)d_in[2];
  const float* w_sel  = (const float*)d_in[3];
  const float* w_off  = (const float*)d_in[4];
  const float* w_om   = (const float*)d_in[5];
  const float* b_om   = (const float*)d_in[6];
  const float* w_dcn  = (const float*)d_in[7];
  const float* b_dcn  = (const float*)d_in[8];
  float* outp = (float*)d_out;

  char* base = (char*)d_ws;
  size_t o = 0;
  float* scale            = (float*)(base + o);          o += 4096;
  float* up               = (float*)(base + o);          o += 16777216;
  float* finecal          = (float*)(base + o);          o += 16777216;
  float* omb              = (float*)(base + o);          o += 14155776;
  unsigned short* alignA  = (unsigned short*)(base + o); o += 16777216;
  unsigned short* alignBf = (unsigned short*)(base + o); o += 16777216;
  unsigned short* w_offT  = (unsigned short*)(base + o); o += 524288;
  unsigned short* w_omT   = (unsigned short*)(base + o); o += 2064384;
  unsigned short* w_dcnT  = (unsigned short*)(base + o); o += 1179648;
  // partial pooling buffer aliases alignBf (dead until gemm_align_mfma)
  float* partial = (float*)alignBf;  // 256 KB

  prep_weights<<<dim3(4032), dim3(256), 0, stream>>>(
      w_off, w_om, w_dcn, w_offT, w_omT, w_dcnT);
  pool_partial<<<dim3(64, 4), dim3(256), 0, stream>>>(fine, partial);
  pool_finish<<<dim3(4), dim3(256), 0, stream>>>(partial, w_att, scale);
  upsample_kernel<<<dim3(16384), dim3(256), 0, stream>>>(coarse, up, alignA);
  gemm_finecal<<<dim3(4, 256), dim3(256), 0, stream>>>(fine, scale, w_sel, finecal, alignA);
  gemm_align_mfma<<<dim3(8, 128), dim3(256), 0, stream>>>(alignA, w_offT, alignBf);
  om_conv_mfma<<<dim3(256, 2), dim3(256), 0, stream>>>(alignBf, w_omT, b_om, omb);
  dcn_mfma<<<dim3(256), dim3(256), 0, stream>>>(omb, up, w_dcnT, b_dcn, finecal, outp);
}